// Round 17
// baseline (90.906 us; speedup 1.0000x reference)
//
#include <hip/hip_runtime.h>

// QRNN fo-pool: B=8, C=256, H=256, T=4096, K=2
// PX: x -> xq single-tap frag-packed bf16 (+ folded W pack)
// G : MFMA GEMM 96m x 128t, 4 waves; A staged via gl16 into 12KB LDS; B loaded
//     DIRECT-TO-REGISTER from frag-packed xq (coalesced 16B/lane, L2-resident,
//     free of the barrier rhythm). LDS 16.6KB -> 8 blocks/CU (wave-limited).
//     Fused bf16 scan epilogue unchanged (r13/r16).
// S2: aggregate scan -> carry_in ; S3: elementwise fixup + h = o*c

typedef unsigned short ushort_t;
typedef __attribute__((ext_vector_type(8))) short short8_t;
typedef __attribute__((ext_vector_type(4))) float f32x4;

#define B_ 8
#define C_ 256
#define H_ 256
#define T_ 4096
#define NCH 128
#define NTF 257        // frag-rows per b: 1 zero row + 256
#define LS2 130        // scan row stride in bf16 (65 words, odd -> conflict-free)

__device__ __forceinline__ unsigned short f2bf(float f) {
  unsigned int u = __float_as_uint(f);
  u += 0x7fffu + ((u >> 16) & 1u);
  return (unsigned short)(u >> 16);
}
__device__ __forceinline__ float bf2f(unsigned short u) {
  return __uint_as_float(((unsigned int)u) << 16);
}
__device__ __forceinline__ float sigm(float v) { return 1.f / (1.f + __expf(-v)); }
__device__ __forceinline__ float tanh_f(float v) { return 2.f / (1.f + __expf(-2.f * v)) - 1.f; }

__device__ __forceinline__ void gl16(const ushort_t* g, ushort_t* l) {
  __builtin_amdgcn_global_load_lds(
      (const __attribute__((address_space(1))) unsigned int*)g,
      (__attribute__((address_space(3))) unsigned int*)l, 16, 0, 0);
}

// ---------------- PX: x transpose/pack + (folded) W pack ---------------------------------
__global__ __launch_bounds__(256) void qrnn_pack_x(const float* __restrict__ x,
                                                   ushort_t* __restrict__ xq,
                                                   const float* __restrict__ Wz,
                                                   const float* __restrict__ Wf,
                                                   const float* __restrict__ Wo,
                                                   ushort_t* __restrict__ aq) {
  __shared__ float tile[32][129];
  const int tid = threadIdx.x;
  const int t0 = blockIdx.x * 128, c0 = blockIdx.y * 32, b = blockIdx.z;
#pragma unroll
  for (int p = 0; p < 4; ++p) {
    const int j = tid + p * 256;
    const int row = j >> 5, q = j & 31;
    float4 v = *reinterpret_cast<const float4*>(x + ((size_t)(b * C_ + c0 + row)) * T_ + t0 + q * 4);
    tile[row][q * 4 + 0] = v.x; tile[row][q * 4 + 1] = v.y;
    tile[row][q * 4 + 2] = v.z; tile[row][q * 4 + 3] = v.w;
  }
  const int ks0 = c0 >> 5;
  if (blockIdx.x == 0 && tid < 64) {    // zero pad frag-row (t = -16..-1)
    uint4 zz = make_uint4(0, 0, 0, 0);
    *reinterpret_cast<uint4*>(xq + ((size_t)(b * NTF) * 8 + ks0) * 512 + tid * 8) = zz;
  }
  // ---- folded PW ----
  const int widx = blockIdx.x + 32 * blockIdx.y;     // 0..255
  if (blockIdx.z == 0 && widx < 192) {
    const int idx = widx * 256 + tid;
    const int lane = idx & 63;
    const int ks = (idx >> 6) & 15;
    const int mf = idx >> 10;
    const int hs8 = mf / 6, rem = mf % 6;
    const int g = rem >> 1, hlf2 = rem & 1;
    const int h = hs8 * 32 + hlf2 * 16 + (lane & 15);
    const float* W = (g == 0) ? Wz : ((g == 1) ? Wf : Wo);
    ushort_t o[8];
#pragma unroll
    for (int j = 0; j < 8; ++j) {
      const int k = ks * 32 + (lane >> 4) * 8 + j;
      const int c = k & 255;
      const int tap = (k < 256) ? 1 : 0;
      o[j] = f2bf(W[((size_t)h * C_ + c) * 2 + tap]);
    }
    *reinterpret_cast<uint4*>(aq + (size_t)idx * 8) = *reinterpret_cast<uint4*>(&o[0]);
  }
  __syncthreads();
#pragma unroll
  for (int q2 = 0; q2 < 2; ++q2) {
    const int p = tid + q2 * 256;
    const int tfl = p >> 6, lane = p & 63;
    const int l15 = lane & 15, g8 = (lane >> 4) * 8;
    const int tcol = tfl * 16 + l15;
    ushort_t o0[8];
#pragma unroll
    for (int j = 0; j < 8; ++j) o0[j] = f2bf(tile[g8 + j][tcol]);
    ushort_t* d0 = xq + ((size_t)(b * NTF + 1 + (t0 >> 4) + tfl) * 8 + ks0) * 512 + lane * 8;
    *reinterpret_cast<uint4*>(d0) = *reinterpret_cast<uint4*>(&o0[0]);
  }
}

// ---------------- G: MFMA GEMM 96m x 128t, A-in-LDS + B-direct-to-reg --------------------
__global__ __launch_bounds__(256, 4) void qrnn_g(const ushort_t* __restrict__ aq,
                                                 const ushort_t* __restrict__ xq,
                                                 const float* __restrict__ bz,
                                                 const float* __restrict__ bfv,
                                                 const float* __restrict__ bo,
                                                 ushort_t* __restrict__ cl,
                                                 ushort_t* __restrict__ pb,
                                                 ushort_t* __restrict__ ob,
                                                 float* __restrict__ aggP,
                                                 float* __restrict__ aggC) {
  __shared__ __align__(16) char ldsu[16640];
  ushort_t* As = (ushort_t*)ldsu;                   // staging: 12 rows x 512 = 12288B
  ushort_t* lzs = (ushort_t*)ldsu;                  // [32][LS2] bf16: z -> c_local (8320B)
  ushort_t* lfs = (ushort_t*)(ldsu + 8320);         // [32][LS2] bf16: f-0.5 -> P

  const int tid = threadIdx.x;
  const int lane = tid & 63;
  const int wid = tid >> 6;
  const int wm = wid >> 1;                          // 0..1 (m-split 2)
  const int wt = wid & 1;                           // 0..1 (t-split 2)
  const int l15 = lane & 15, g4 = lane >> 4;
  const int bid = blockIdx.x;
  const int b = bid & 7;                            // XCD-local batch
  const int hs8 = (bid >> 3) & 7;                   // 32-h strip
  const int tt = bid >> 6;                          // 0..31, 128 t-cols each

  const int sh0 = (l15 == 0) ? 1 : 0;
  const int lane0 = lane + (sh0 ? 15 : -1);

  // B direct base (tap1): frag(l,n,kk_local) at Bbase + n*4096 + kkl*1024 + l*512 (elements)
  const ushort_t* Bbase =
      xq + ((size_t)(b * NTF + 1 + tt * 8 + wt * 4) * 8) * 512 + lane * 8;

  f32x4 acc[3][4];
#pragma unroll
  for (int i = 0; i < 3; ++i)
#pragma unroll
    for (int n = 0; n < 4; ++n) acc[i][n] = (f32x4){0.f, 0.f, 0.f, 0.f};

  for (int half = 0; half < 2; ++half) {
    for (int kkl = 0; kkl < 4; ++kkl) {
      const int kk = half * 4 + kkl;
      // ---- stage A only: 3 gl16 per thread ----
#pragma unroll
      for (int q = 0; q < 3; ++q) {
        const int c = tid + q * 256;                // [0,768)
        const int row = c >> 6;                     // mfl*2+ksl, 12 rows
        const int mfl = row >> 1, ksl = row & 1;
        gl16(aq + (((size_t)(hs8 * 6 + mfl) * 16 + kk * 2 + ksl) << 9) + lane * 8,
             As + (size_t)(c - lane) * 8);
      }
      __syncthreads();
      // ---- compute: B frags direct from global (L2), A from LDS ----
#pragma unroll
      for (int l = 0; l < 2; ++l) {
        short8_t bb[4];
#pragma unroll
        for (int n = 0; n < 4; ++n)
          bb[n] = *reinterpret_cast<const short8_t*>(Bbase + n * 4096 + kkl * 1024 + l * 512);
#pragma unroll
        for (int i = 0; i < 3; ++i) {
          const int row = (wm * 3 + i) * 2 + l;
          short8_t a = *reinterpret_cast<const short8_t*>(&As[(size_t)(row * 64 + lane) * 8]);
#pragma unroll
          for (int n = 0; n < 4; ++n)
            acc[i][n] = __builtin_amdgcn_mfma_f32_16x16x32_bf16(a, bb[n], acc[i][n], 0, 0, 0);
        }
      }
      __syncthreads();
    }
    if (half == 0)  // switch to tap0: shift frag-row by -sh0 and lane -> lane0
      Bbase += (ptrdiff_t)(lane0 - lane) * 8 - (ptrdiff_t)sh0 * 4096;
  }

  // ---- epilogue B1: bias+act; z -> lzs, (f-0.5) -> lfs, o -> global bf16 ----
#pragma unroll
  for (int i = 0; i < 3; ++i) {
    const int mfl = wm * 3 + i;          // 0..5
    const int g = mfl >> 1;              // 0=z 1=f 2=o
    const int hlf2 = mfl & 1;
    const float* bias = (g == 0) ? bz : ((g == 1) ? bfv : bo);
#pragma unroll
    for (int r = 0; r < 4; ++r) {
      const int hl = hlf2 * 16 + g4 * 4 + r;           // [0,32); C/D: row=(lane>>4)*4+reg
      const float bvv = bias[hs8 * 32 + hl];
#pragma unroll
      for (int n = 0; n < 4; ++n) {
        const int tl = wt * 64 + n * 16 + l15;         // C/D: col=lane&15; [0,128)
        const float v = acc[i][n][r] + bvv;
        if (g == 0)      lzs[hl * LS2 + tl] = f2bf(tanh_f(v));
        else if (g == 1) lfs[hl * LS2 + tl] = f2bf(sigm(v) - 0.5f);
        else ob[((size_t)b * H_ + hs8 * 32 + hl) * T_ + tt * 128 + tl] = f2bf(sigm(v));
      }
    }
  }
  __syncthreads();

  // ---- B2: chunk=32 scan, in place: z->c_local, f->P; aggregates out ----
  if (tid < 128) {
    const int h = tid & 31, ch = tid >> 5;          // 32 h x 4 chunks
    const int base = h * LS2 + ch * 32;
    float c = 0.f, p = 1.f;
#pragma unroll
    for (int u = 0; u < 16; ++u) {
      unsigned vz = *reinterpret_cast<const unsigned*>(&lzs[base + 2 * u]);
      unsigned vf = *reinterpret_cast<const unsigned*>(&lfs[base + 2 * u]);
      const float f0 = bf2f((ushort_t)(vf & 0xffff)) + 0.5f;
      const float z0 = bf2f((ushort_t)(vz & 0xffff));
      c = f0 * (c - z0) + z0; p *= f0;
      const float cl0 = c, pl0 = p;
      const float f1 = bf2f((ushort_t)(vf >> 16)) + 0.5f;
      const float z1 = bf2f((ushort_t)(vz >> 16));
      c = f1 * (c - z1) + z1; p *= f1;
      *reinterpret_cast<unsigned*>(&lzs[base + 2 * u]) =
          (unsigned)f2bf(cl0) | ((unsigned)f2bf(c) << 16);
      *reinterpret_cast<unsigned*>(&lfs[base + 2 * u]) =
          (unsigned)f2bf(pl0) | ((unsigned)f2bf(p) << 16);
    }
    const int chunkg = tt * 4 + ch;
    aggP[((size_t)b * NCH + chunkg) * H_ + hs8 * 32 + h] = p;
    aggC[((size_t)b * NCH + chunkg) * H_ + hs8 * 32 + h] = c;
  }
  __syncthreads();

  // ---- B3: coalesced write-out: c_local bf16, P bf16 ----
  const size_t gb = ((size_t)b * H_ + hs8 * 32) * T_ + tt * 128;
#pragma unroll
  for (int q = 0; q < 2; ++q) {
    const int j = tid + q * 256;         // 512 uint4 units over [32][128] bf16
    const int row = j >> 4, col8 = (j & 15) * 8;
    const int base = row * LS2 + col8;
    uint4 pk;
    pk.x = *reinterpret_cast<const unsigned*>(&lzs[base]);
    pk.y = *reinterpret_cast<const unsigned*>(&lzs[base + 2]);
    pk.z = *reinterpret_cast<const unsigned*>(&lzs[base + 4]);
    pk.w = *reinterpret_cast<const unsigned*>(&lzs[base + 6]);
    *reinterpret_cast<uint4*>(cl + gb + (size_t)row * T_ + col8) = pk;
    pk.x = *reinterpret_cast<const unsigned*>(&lfs[base]);
    pk.y = *reinterpret_cast<const unsigned*>(&lfs[base + 2]);
    pk.z = *reinterpret_cast<const unsigned*>(&lfs[base + 4]);
    pk.w = *reinterpret_cast<const unsigned*>(&lfs[base + 6]);
    *reinterpret_cast<uint4*>(pb + gb + (size_t)row * T_ + col8) = pk;
  }
}

// ---------------- S2: scan over chunk aggregates -> carry_in -----------------------------
__global__ __launch_bounds__(256) void qrnn_s2(const float* __restrict__ aggP,
                                               const float* __restrict__ aggC,
                                               float* __restrict__ cin) {
  const int b = blockIdx.x, h = threadIdx.x;
  float carry = 0.f;
  for (int jb = 0; jb < NCH; jb += 8) {
    float P[8], Cv[8];
#pragma unroll
    for (int u = 0; u < 8; ++u) {
      P[u] = aggP[((size_t)b * NCH + jb + u) * H_ + h];
      Cv[u] = aggC[((size_t)b * NCH + jb + u) * H_ + h];
    }
#pragma unroll
    for (int u = 0; u < 8; ++u) {
      cin[((size_t)b * NCH + jb + u) * H_ + h] = carry;
      carry = Cv[u] + P[u] * carry;
    }
  }
}

// ---------------- S3: elementwise c = cl + P*carry; h = o*c ------------------------------
__global__ __launch_bounds__(256) void qrnn_s3(const ushort_t* __restrict__ cl,
                                               const ushort_t* __restrict__ pb,
                                               const ushort_t* __restrict__ ob,
                                               const float* __restrict__ cin,
                                               float* __restrict__ outc,
                                               float* __restrict__ outh) {
  const int n4 = B_ * H_ * T_ / 4;
  for (int i4 = blockIdx.x * 256 + threadIdx.x; i4 < n4; i4 += gridDim.x * 256) {
    const int idx = i4 << 2;
    const int t = idx & (T_ - 1);
    const int bh = idx >> 12;
    const float carry = cin[((size_t)(bh >> 8) * NCH + (t >> 5)) * H_ + (bh & 255)];
    uint2 cv2 = reinterpret_cast<const uint2*>(cl)[i4];
    uint2 pv = reinterpret_cast<const uint2*>(pb)[i4];
    uint2 ov = reinterpret_cast<const uint2*>(ob)[i4];
    const float c0 = bf2f((ushort_t)(cv2.x & 0xffff)) + bf2f((ushort_t)(pv.x & 0xffff)) * carry;
    const float c1 = bf2f((ushort_t)(cv2.x >> 16)) + bf2f((ushort_t)(pv.x >> 16)) * carry;
    const float c2 = bf2f((ushort_t)(cv2.y & 0xffff)) + bf2f((ushort_t)(pv.y & 0xffff)) * carry;
    const float c3 = bf2f((ushort_t)(cv2.y >> 16)) + bf2f((ushort_t)(pv.y >> 16)) * carry;
    reinterpret_cast<float4*>(outc)[i4] = make_float4(c0, c1, c2, c3);
    reinterpret_cast<float4*>(outh)[i4] =
        make_float4(bf2f((ushort_t)(ov.x & 0xffff)) * c0, bf2f((ushort_t)(ov.x >> 16)) * c1,
                    bf2f((ushort_t)(ov.y & 0xffff)) * c2, bf2f((ushort_t)(ov.y >> 16)) * c3);
  }
}

extern "C" void kernel_launch(void* const* d_in, const int* in_sizes, int n_in,
                              void* d_out, int out_size, void* d_ws, size_t ws_size,
                              hipStream_t stream) {
  const float* x  = (const float*)d_in[0];
  const float* Wz = (const float*)d_in[1];
  const float* bz = (const float*)d_in[2];
  const float* Wf = (const float*)d_in[3];
  const float* bfv= (const float*)d_in[4];
  const float* Wo = (const float*)d_in[5];
  const float* bo = (const float*)d_in[6];

  float* outh = (float*)d_out;                        // [B][H][T]
  float* outc = outh + (size_t)B_ * H_ * T_;          // [B][H][T]

  constexpr size_t XQ_OFF  = 0;                       // 16,842,752
  constexpr size_t AQ_OFF  = 16842752;                //    786,432
  constexpr size_t CL_OFF  = 17629184;                // 16,777,216 (c_local bf16)
  constexpr size_t PB_OFF  = 34406400;                // 16,777,216 (P bf16)
  constexpr size_t OB_OFF  = 51183616;                // 16,777,216 (o bf16)
  constexpr size_t AGP_OFF = 67960832;                //  1,048,576
  constexpr size_t AGC_OFF = 69009408;                //  1,048,576
  constexpr size_t CIN_OFF = 70057984;                //  1,048,576
  constexpr size_t WS_NEED = 71106560;
  if (ws_size < WS_NEED) return;

  ushort_t* xq  = (ushort_t*)((char*)d_ws + XQ_OFF);
  ushort_t* aq  = (ushort_t*)((char*)d_ws + AQ_OFF);
  ushort_t* clb = (ushort_t*)((char*)d_ws + CL_OFF);
  ushort_t* pbb = (ushort_t*)((char*)d_ws + PB_OFF);
  ushort_t* ob  = (ushort_t*)((char*)d_ws + OB_OFF);
  float* aggP   = (float*)((char*)d_ws + AGP_OFF);
  float* aggC   = (float*)((char*)d_ws + AGC_OFF);
  float* cin    = (float*)((char*)d_ws + CIN_OFF);

  qrnn_pack_x<<<dim3(T_ / 128, C_ / 32, B_), 256, 0, stream>>>(x, xq, Wz, Wf, Wo, aq);
  qrnn_g<<<dim3(2048), 256, 0, stream>>>(aq, xq, bz, bfv, bo, clb, pbb, ob, aggP, aggC);
  qrnn_s2<<<dim3(B_), 256, 0, stream>>>(aggP, aggC, cin);
  qrnn_s3<<<dim3(2048), 256, 0, stream>>>(clb, pbb, ob, cin, outc, outh);
}

// Round 18
// 89.427 us; speedup vs baseline: 1.0165x; 1.0165x over previous
//
#include <hip/hip_runtime.h>

// QRNN fo-pool: B=8, C=256, H=256, T=4096, K=2  — FINAL CHAMPION (r16 config)
// PX: x -> xq single-tap frag-packed bf16 (zero pad frag-row at t=-1); blocks
//     (z==0, x+32y<192) also pack W -> aq frag-packed [hs8][gate][hlf2].
// G : MFMA GEMM 96m x 128t, 4 waves (2m x 2t, wave 48x64), BK=64, gl16 staging,
//     tap-0 via shifted-lane source addresses, 28KB LDS (5 blocks/CU);
//     fused bf16 scan epilogue: z,(f-0.5)->LDS, chunk=32 scan, c_local/P/o bf16 out.
// S2: aggregate scan -> carry_in
// S3: elementwise c = cl + P*carry; h = o*c
// Session notes: VGPR budget = 256/launch_bounds_arg2 (empirical); 9 gates variants
// (pipelining x3, zero-LDS, big-tile, occupancy x2, addr-SR, B-direct) all land
// 51-65µs -> ~51µs is this structure's latency plateau. 123.8 -> 88.2µs overall.

typedef unsigned short ushort_t;
typedef __attribute__((ext_vector_type(8))) short short8_t;
typedef __attribute__((ext_vector_type(4))) float f32x4;

#define B_ 8
#define C_ 256
#define H_ 256
#define T_ 4096
#define NCH 128
#define NTF 257        // frag-rows per b: 1 zero row + 256
#define LS2 130        // scan row stride in bf16 (65 words, odd -> conflict-free)

__device__ __forceinline__ unsigned short f2bf(float f) {
  unsigned int u = __float_as_uint(f);
  u += 0x7fffu + ((u >> 16) & 1u);
  return (unsigned short)(u >> 16);
}
__device__ __forceinline__ float bf2f(unsigned short u) {
  return __uint_as_float(((unsigned int)u) << 16);
}
__device__ __forceinline__ float sigm(float v) { return 1.f / (1.f + __expf(-v)); }
__device__ __forceinline__ float tanh_f(float v) { return 2.f / (1.f + __expf(-2.f * v)) - 1.f; }

__device__ __forceinline__ void gl16(const ushort_t* g, ushort_t* l) {
  __builtin_amdgcn_global_load_lds(
      (const __attribute__((address_space(1))) unsigned int*)g,
      (__attribute__((address_space(3))) unsigned int*)l, 16, 0, 0);
}

// ---------------- PX: x transpose/pack + (folded) W pack ---------------------------------
// xq[((b*NTF + 1 + tf)*8 + ks)*512 + lane*8 + j] = bf16(x[b][32ks+(lane>>4)*8+j][16tf+(lane&15)])
__global__ __launch_bounds__(256) void qrnn_pack_x(const float* __restrict__ x,
                                                   ushort_t* __restrict__ xq,
                                                   const float* __restrict__ Wz,
                                                   const float* __restrict__ Wf,
                                                   const float* __restrict__ Wo,
                                                   ushort_t* __restrict__ aq) {
  __shared__ float tile[32][129];
  const int tid = threadIdx.x;
  const int t0 = blockIdx.x * 128, c0 = blockIdx.y * 32, b = blockIdx.z;
#pragma unroll
  for (int p = 0; p < 4; ++p) {
    const int j = tid + p * 256;
    const int row = j >> 5, q = j & 31;
    float4 v = *reinterpret_cast<const float4*>(x + ((size_t)(b * C_ + c0 + row)) * T_ + t0 + q * 4);
    tile[row][q * 4 + 0] = v.x; tile[row][q * 4 + 1] = v.y;
    tile[row][q * 4 + 2] = v.z; tile[row][q * 4 + 3] = v.w;
  }
  const int ks0 = c0 >> 5;
  if (blockIdx.x == 0 && tid < 64) {    // zero pad frag-row (t = -16..-1)
    uint4 zz = make_uint4(0, 0, 0, 0);
    *reinterpret_cast<uint4*>(xq + ((size_t)(b * NTF) * 8 + ks0) * 512 + tid * 8) = zz;
  }
  // ---- folded PW: blocks (z==0, x+32y<192) pack one 256-element strip of aq ----
  const int widx = blockIdx.x + 32 * blockIdx.y;     // 0..255
  if (blockIdx.z == 0 && widx < 192) {
    const int idx = widx * 256 + tid;                // < 48*16*64
    const int lane = idx & 63;
    const int ks = (idx >> 6) & 15;
    const int mf = idx >> 10;                        // 0..47
    const int hs8 = mf / 6, rem = mf % 6;
    const int g = rem >> 1, hlf2 = rem & 1;
    const int h = hs8 * 32 + hlf2 * 16 + (lane & 15);
    const float* W = (g == 0) ? Wz : ((g == 1) ? Wf : Wo);
    ushort_t o[8];
#pragma unroll
    for (int j = 0; j < 8; ++j) {
      const int k = ks * 32 + (lane >> 4) * 8 + j;
      const int c = k & 255;
      const int tap = (k < 256) ? 1 : 0;
      o[j] = f2bf(W[((size_t)h * C_ + c) * 2 + tap]);
    }
    *reinterpret_cast<uint4*>(aq + (size_t)idx * 8) = *reinterpret_cast<uint4*>(&o[0]);
  }
  __syncthreads();
#pragma unroll
  for (int q2 = 0; q2 < 2; ++q2) {
    const int p = tid + q2 * 256;
    const int tfl = p >> 6, lane = p & 63;
    const int l15 = lane & 15, g8 = (lane >> 4) * 8;
    const int tcol = tfl * 16 + l15;
    ushort_t o0[8];
#pragma unroll
    for (int j = 0; j < 8; ++j) o0[j] = f2bf(tile[g8 + j][tcol]);
    ushort_t* d0 = xq + ((size_t)(b * NTF + 1 + (t0 >> 4) + tfl) * 8 + ks0) * 512 + lane * 8;
    *reinterpret_cast<uint4*>(d0) = *reinterpret_cast<uint4*>(&o0[0]);
  }
}

// ---------------- G: MFMA GEMM 96m x 128t + fused chunk-scan epilogue --------------------
__global__ __launch_bounds__(256, 4) void qrnn_g(const ushort_t* __restrict__ aq,
                                                 const ushort_t* __restrict__ xq,
                                                 const float* __restrict__ bz,
                                                 const float* __restrict__ bfv,
                                                 const float* __restrict__ bo,
                                                 ushort_t* __restrict__ cl,
                                                 ushort_t* __restrict__ pb,
                                                 ushort_t* __restrict__ ob,
                                                 float* __restrict__ aggP,
                                                 float* __restrict__ aggC) {
  __shared__ __align__(16) char ldsu[28672];
  ushort_t* As = (ushort_t*)ldsu;                   // [mfl*2+ksl][lane][8]  12 rows, 12288B
  ushort_t* Bs = (ushort_t*)(ldsu + 12288);         // [tfl*2+ksl][lane][8]  16 rows, 16384B
  ushort_t* lzs = (ushort_t*)ldsu;                  // [32][LS2] bf16: z -> c_local (8320B)
  ushort_t* lfs = (ushort_t*)(ldsu + 8320);         // [32][LS2] bf16: f-0.5 -> P

  const int tid = threadIdx.x;
  const int lane = tid & 63;
  const int wid = tid >> 6;
  const int wm = wid >> 1;                          // 0..1 (m-split 2)
  const int wt = wid & 1;                           // 0..1 (t-split 2)
  const int l15 = lane & 15, g4 = lane >> 4;
  const int bid = blockIdx.x;
  const int b = bid & 7;                            // XCD-local batch
  const int hs8 = (bid >> 3) & 7;                   // 32-h strip
  const int tt = bid >> 6;                          // 0..31, 128 t-cols each

  const int sh0 = (l15 == 0) ? 1 : 0;
  const int lane0 = lane + (sh0 ? 15 : -1);

  f32x4 acc[3][4];
#pragma unroll
  for (int i = 0; i < 3; ++i)
#pragma unroll
    for (int n = 0; n < 4; ++n) acc[i][n] = (f32x4){0.f, 0.f, 0.f, 0.f};

  for (int kk = 0; kk < 8; ++kk) {
    // ---- stage: 3 A + 4 B gl16 per thread, linear LDS dest ----
#pragma unroll
    for (int q = 0; q < 3; ++q) {
      const int c = tid + q * 256;                  // [0,768)
      const int row = c >> 6;                       // mfl*2+ksl, 12 rows
      const int mfl = row >> 1, ksl = row & 1;
      gl16(aq + (((size_t)(hs8 * 6 + mfl) * 16 + kk * 2 + ksl) << 9) + lane * 8,
           As + (size_t)(c - lane) * 8);
    }
#pragma unroll
    for (int q = 0; q < 4; ++q) {
      const int c2 = tid + q * 256;                 // [0,1024)
      const int row = c2 >> 6;                      // tfl*2+ksl, 16 rows
      const int tfl = row >> 1, ksl = row & 1;
      const int kg = kk * 2 + ksl;
      const ushort_t* src;
      if (kg < 8)
        src = xq + (((size_t)(b * NTF + 1 + tt * 8 + tfl) * 8 + kg) << 9) + lane * 8;
      else
        src = xq + (((size_t)(b * NTF + 1 + tt * 8 + tfl - sh0) * 8 + (kg - 8)) << 9) + lane0 * 8;
      gl16(src, Bs + (size_t)(c2 - lane) * 8);
    }
    __syncthreads();
    // ---- compute: per ksl: preload bb[4], then i-loop {read a, 4 MFMA} ----
#pragma unroll
    for (int l = 0; l < 2; ++l) {
      short8_t bb[4];
#pragma unroll
      for (int n = 0; n < 4; ++n) {
        const int row = (wt * 4 + n) * 2 + l;
        bb[n] = *reinterpret_cast<const short8_t*>(&Bs[(size_t)(row * 64 + lane) * 8]);
      }
#pragma unroll
      for (int i = 0; i < 3; ++i) {
        const int row = (wm * 3 + i) * 2 + l;
        short8_t a = *reinterpret_cast<const short8_t*>(&As[(size_t)(row * 64 + lane) * 8]);
#pragma unroll
        for (int n = 0; n < 4; ++n)
          acc[i][n] = __builtin_amdgcn_mfma_f32_16x16x32_bf16(a, bb[n], acc[i][n], 0, 0, 0);
      }
    }
    __syncthreads();
  }

  // ---- epilogue B1: bias+act; z -> lzs, (f-0.5) -> lfs, o -> global bf16 ----
#pragma unroll
  for (int i = 0; i < 3; ++i) {
    const int mfl = wm * 3 + i;          // 0..5
    const int g = mfl >> 1;              // 0=z 1=f 2=o
    const int hlf2 = mfl & 1;
    const float* bias = (g == 0) ? bz : ((g == 1) ? bfv : bo);
#pragma unroll
    for (int r = 0; r < 4; ++r) {
      const int hl = hlf2 * 16 + g4 * 4 + r;           // [0,32); C/D: row=(lane>>4)*4+reg
      const float bvv = bias[hs8 * 32 + hl];
#pragma unroll
      for (int n = 0; n < 4; ++n) {
        const int tl = wt * 64 + n * 16 + l15;         // C/D: col=lane&15; [0,128)
        const float v = acc[i][n][r] + bvv;
        if (g == 0)      lzs[hl * LS2 + tl] = f2bf(tanh_f(v));
        else if (g == 1) lfs[hl * LS2 + tl] = f2bf(sigm(v) - 0.5f);
        else ob[((size_t)b * H_ + hs8 * 32 + hl) * T_ + tt * 128 + tl] = f2bf(sigm(v));
      }
    }
  }
  __syncthreads();

  // ---- B2: chunk=32 scan, in place: z->c_local, f->P; aggregates out ----
  if (tid < 128) {
    const int h = tid & 31, ch = tid >> 5;          // 32 h x 4 chunks
    const int base = h * LS2 + ch * 32;
    float c = 0.f, p = 1.f;
#pragma unroll
    for (int u = 0; u < 16; ++u) {
      unsigned vz = *reinterpret_cast<const unsigned*>(&lzs[base + 2 * u]);
      unsigned vf = *reinterpret_cast<const unsigned*>(&lfs[base + 2 * u]);
      const float f0 = bf2f((ushort_t)(vf & 0xffff)) + 0.5f;
      const float z0 = bf2f((ushort_t)(vz & 0xffff));
      c = f0 * (c - z0) + z0; p *= f0;
      const float cl0 = c, pl0 = p;
      const float f1 = bf2f((ushort_t)(vf >> 16)) + 0.5f;
      const float z1 = bf2f((ushort_t)(vz >> 16));
      c = f1 * (c - z1) + z1; p *= f1;
      *reinterpret_cast<unsigned*>(&lzs[base + 2 * u]) =
          (unsigned)f2bf(cl0) | ((unsigned)f2bf(c) << 16);
      *reinterpret_cast<unsigned*>(&lfs[base + 2 * u]) =
          (unsigned)f2bf(pl0) | ((unsigned)f2bf(p) << 16);
    }
    const int chunkg = tt * 4 + ch;
    aggP[((size_t)b * NCH + chunkg) * H_ + hs8 * 32 + h] = p;
    aggC[((size_t)b * NCH + chunkg) * H_ + hs8 * 32 + h] = c;
  }
  __syncthreads();

  // ---- B3: coalesced write-out: c_local bf16, P bf16 ----
  const size_t gb = ((size_t)b * H_ + hs8 * 32) * T_ + tt * 128;
#pragma unroll
  for (int q = 0; q < 2; ++q) {
    const int j = tid + q * 256;         // 512 uint4 units over [32][128] bf16
    const int row = j >> 4, col8 = (j & 15) * 8;
    const int base = row * LS2 + col8;
    uint4 pk;
    pk.x = *reinterpret_cast<const unsigned*>(&lzs[base]);
    pk.y = *reinterpret_cast<const unsigned*>(&lzs[base + 2]);
    pk.z = *reinterpret_cast<const unsigned*>(&lzs[base + 4]);
    pk.w = *reinterpret_cast<const unsigned*>(&lzs[base + 6]);
    *reinterpret_cast<uint4*>(cl + gb + (size_t)row * T_ + col8) = pk;
    pk.x = *reinterpret_cast<const unsigned*>(&lfs[base]);
    pk.y = *reinterpret_cast<const unsigned*>(&lfs[base + 2]);
    pk.z = *reinterpret_cast<const unsigned*>(&lfs[base + 4]);
    pk.w = *reinterpret_cast<const unsigned*>(&lfs[base + 6]);
    *reinterpret_cast<uint4*>(pb + gb + (size_t)row * T_ + col8) = pk;
  }
}

// ---------------- S2: scan over chunk aggregates -> carry_in -----------------------------
__global__ __launch_bounds__(256) void qrnn_s2(const float* __restrict__ aggP,
                                               const float* __restrict__ aggC,
                                               float* __restrict__ cin) {
  const int b = blockIdx.x, h = threadIdx.x;
  float carry = 0.f;
  for (int jb = 0; jb < NCH; jb += 8) {
    float P[8], Cv[8];
#pragma unroll
    for (int u = 0; u < 8; ++u) {
      P[u] = aggP[((size_t)b * NCH + jb + u) * H_ + h];
      Cv[u] = aggC[((size_t)b * NCH + jb + u) * H_ + h];
    }
#pragma unroll
    for (int u = 0; u < 8; ++u) {
      cin[((size_t)b * NCH + jb + u) * H_ + h] = carry;
      carry = Cv[u] + P[u] * carry;
    }
  }
}

// ---------------- S3: elementwise c = cl + P*carry; h = o*c ------------------------------
__global__ __launch_bounds__(256) void qrnn_s3(const ushort_t* __restrict__ cl,
                                               const ushort_t* __restrict__ pb,
                                               const ushort_t* __restrict__ ob,
                                               const float* __restrict__ cin,
                                               float* __restrict__ outc,
                                               float* __restrict__ outh) {
  const int n4 = B_ * H_ * T_ / 4;
  for (int i4 = blockIdx.x * 256 + threadIdx.x; i4 < n4; i4 += gridDim.x * 256) {
    const int idx = i4 << 2;
    const int t = idx & (T_ - 1);
    const int bh = idx >> 12;
    const float carry = cin[((size_t)(bh >> 8) * NCH + (t >> 5)) * H_ + (bh & 255)];
    uint2 cv2 = reinterpret_cast<const uint2*>(cl)[i4];
    uint2 pv = reinterpret_cast<const uint2*>(pb)[i4];
    uint2 ov = reinterpret_cast<const uint2*>(ob)[i4];
    const float c0 = bf2f((ushort_t)(cv2.x & 0xffff)) + bf2f((ushort_t)(pv.x & 0xffff)) * carry;
    const float c1 = bf2f((ushort_t)(cv2.x >> 16)) + bf2f((ushort_t)(pv.x >> 16)) * carry;
    const float c2 = bf2f((ushort_t)(cv2.y & 0xffff)) + bf2f((ushort_t)(pv.y & 0xffff)) * carry;
    const float c3 = bf2f((ushort_t)(cv2.y >> 16)) + bf2f((ushort_t)(pv.y >> 16)) * carry;
    reinterpret_cast<float4*>(outc)[i4] = make_float4(c0, c1, c2, c3);
    reinterpret_cast<float4*>(outh)[i4] =
        make_float4(bf2f((ushort_t)(ov.x & 0xffff)) * c0, bf2f((ushort_t)(ov.x >> 16)) * c1,
                    bf2f((ushort_t)(ov.y & 0xffff)) * c2, bf2f((ushort_t)(ov.y >> 16)) * c3);
  }
}

extern "C" void kernel_launch(void* const* d_in, const int* in_sizes, int n_in,
                              void* d_out, int out_size, void* d_ws, size_t ws_size,
                              hipStream_t stream) {
  const float* x  = (const float*)d_in[0];
  const float* Wz = (const float*)d_in[1];
  const float* bz = (const float*)d_in[2];
  const float* Wf = (const float*)d_in[3];
  const float* bfv= (const float*)d_in[4];
  const float* Wo = (const float*)d_in[5];
  const float* bo = (const float*)d_in[6];

  float* outh = (float*)d_out;                        // [B][H][T]
  float* outc = outh + (size_t)B_ * H_ * T_;          // [B][H][T]

  constexpr size_t XQ_OFF  = 0;                       // 16,842,752
  constexpr size_t AQ_OFF  = 16842752;                //    786,432
  constexpr size_t CL_OFF  = 17629184;                // 16,777,216 (c_local bf16)
  constexpr size_t PB_OFF  = 34406400;                // 16,777,216 (P bf16)
  constexpr size_t OB_OFF  = 51183616;                // 16,777,216 (o bf16)
  constexpr size_t AGP_OFF = 67960832;                //  1,048,576
  constexpr size_t AGC_OFF = 69009408;                //  1,048,576
  constexpr size_t CIN_OFF = 70057984;                //  1,048,576
  constexpr size_t WS_NEED = 71106560;
  if (ws_size < WS_NEED) return;

  ushort_t* xq  = (ushort_t*)((char*)d_ws + XQ_OFF);
  ushort_t* aq  = (ushort_t*)((char*)d_ws + AQ_OFF);
  ushort_t* clb = (ushort_t*)((char*)d_ws + CL_OFF);
  ushort_t* pbb = (ushort_t*)((char*)d_ws + PB_OFF);
  ushort_t* ob  = (ushort_t*)((char*)d_ws + OB_OFF);
  float* aggP   = (float*)((char*)d_ws + AGP_OFF);
  float* aggC   = (float*)((char*)d_ws + AGC_OFF);
  float* cin    = (float*)((char*)d_ws + CIN_OFF);

  qrnn_pack_x<<<dim3(T_ / 128, C_ / 32, B_), 256, 0, stream>>>(x, xq, Wz, Wf, Wo, aq);
  qrnn_g<<<dim3(2048), 256, 0, stream>>>(aq, xq, bz, bfv, bo, clb, pbb, ob, aggP, aggC);
  qrnn_s2<<<dim3(B_), 256, 0, stream>>>(aggP, aggC, cin);
  qrnn_s3<<<dim3(2048), 256, 0, stream>>>(clb, pbb, ob, cin, outc, outh);
}